// Round 9
// baseline (218.628 us; speedup 1.0000x reference)
//
#include <hip/hip_runtime.h>

// SpikingNeuralNetwork: fc1 (split-bf16x3 MFMA GEMM, fused LIF scan) + sparse fc2.
// R9: 8 waves x 128x64 wave tile (acc=128 regs -> 2 waves/SIMD TLP), BK=16,
// triple-buffered LDS (96KB) staging kt+2 (never-drain vmcnt(4)), R8-style
// pinned lgkm groups. Scan: 4 rounds x 64 t, [col][68] layout.

typedef __attribute__((ext_vector_type(16))) float f32x16;
typedef __attribute__((ext_vector_type(8))) short s16x8;

#define GPTR(p) ((const __attribute__((address_space(1))) void*)(p))
#define SPTR(p) ((__attribute__((address_space(3))) void*)(p))

static constexpr int Bsz = 64, Tsz = 256, Isz = 1024, Hsz = 2048, Osz = 1024;
static constexpr int BK = 16;          // fp32-k per K-tile
static constexpr int NKT = Isz / BK;   // 64
// regions (ushort el): Ah, Al, Bh, Bl each 256x16 = 4096 el (8KB)
static constexpr int REG = 4096;
static constexpr int AH_OFF = 0, AL_OFF = REG, BH_OFF = 2 * REG, BL_OFF = 3 * REG;
static constexpr int BUFEL = 4 * REG;  // 32KB per K-tile buffer, x3 = 96KB
static constexpr int ST = 68;          // scan [col][t] stride (f32), 16B-aligned
static constexpr int LDS_USHORTS = 3 * BUFEL;  // 98304 B; scan (256*68*4=69.6KB) fits

__device__ __forceinline__ unsigned short f2bf(float f) {
  unsigned u = __float_as_uint(f);
  u += 0x7FFFu + ((u >> 16) & 1u);
  return (unsigned short)(u >> 16);
}
__device__ __forceinline__ float bf2f(unsigned short h) {
  return __uint_as_float(((unsigned)h) << 16);
}

// ---------------- kernel 1: split x into hi/lo bf16 ----------------
__global__ void split_x_kernel(const float* __restrict__ x,
                               unsigned short* __restrict__ hi,
                               unsigned short* __restrict__ lo) {
  const long i = (long)blockIdx.x * 256 + threadIdx.x;
  const float4 v = ((const float4*)x)[i];
  const unsigned short hx = f2bf(v.x), hy = f2bf(v.y), hz = f2bf(v.z), hw = f2bf(v.w);
  ushort4 H, L;
  H.x = hx; H.y = hy; H.z = hz; H.w = hw;
  L.x = f2bf(v.x - bf2f(hx));
  L.y = f2bf(v.y - bf2f(hy));
  L.z = f2bf(v.z - bf2f(hz));
  L.w = f2bf(v.w - bf2f(hw));
  ((ushort4*)hi)[i] = H;
  ((ushort4*)lo)[i] = L;
}

// ------- kernel 2: W1 [I][H] -> transposed bf16 hi/lo [H][I] -------
__global__ void w1_transpose_split_kernel(const float* __restrict__ W1,
                                          unsigned short* __restrict__ wh,
                                          unsigned short* __restrict__ wl) {
  __shared__ float tile[32][33];
  const int h0 = blockIdx.x * 32;
  const int i0 = blockIdx.y * 32;
  const int c = threadIdx.x & 31;
  const int r4 = threadIdx.x >> 5;
#pragma unroll
  for (int s = 0; s < 4; ++s) {
    const int r = r4 + s * 8;
    tile[r][c] = W1[(long)(i0 + r) * Hsz + h0 + c];
  }
  __syncthreads();
#pragma unroll
  for (int s = 0; s < 4; ++s) {
    const int hr = r4 + s * 8;
    const float v = tile[c][hr];
    const unsigned short hh = f2bf(v);
    wh[(long)(h0 + hr) * Isz + i0 + c] = hh;
    wl[(long)(h0 + hr) * Isz + i0 + c] = f2bf(v - bf2f(hh));
  }
}

// ---- kernel 3: fused GEMM1 (split-bf16x3, 32x32x16 MFMA) + LIF scan ----
// grid (8 hblk, 64 b), 512 threads = 8 waves (2M x 4N); wave tile 128x64.
__global__ __launch_bounds__(512, 2) void gemm1_scan_kernel(
    const unsigned short* __restrict__ xh, const unsigned short* __restrict__ xl,
    const unsigned short* __restrict__ wth, const unsigned short* __restrict__ wtl,
    const float* __restrict__ b1, float* __restrict__ spk) {
  __shared__ __align__(16) unsigned short lds[LDS_USHORTS];  // 96KB

  const int tid = threadIdx.x;
  const int l = tid & 63;
  const int w = tid >> 6;
  const int wm = w >> 2;  // 0..1 (M: t rows, 128 each)
  const int wn = w & 3;   // 0..3 (N: h cols, 64 each)
  const int b = blockIdx.y;
  const int hb = blockIdx.x * 256;

  // --- staging: one gload instr per region per kt (512 thr x 16B = 8KB) ---
  const int srow = tid >> 1;            // 0..255
  const int gch8 = (tid & 1) * 8;       // linear: row-major [256][16], no swizzle
  const unsigned short* gAh = xh + (long)(b * Tsz + srow) * Isz + gch8;
  const unsigned short* gAl = xl + (long)(b * Tsz + srow) * Isz + gch8;
  const unsigned short* gBh = wth + (long)(hb + srow) * Isz + gch8;
  const unsigned short* gBl = wtl + (long)(hb + srow) * Isz + gch8;

#define STG(OFF, G, Q, KT) do {                                                           \
    unsigned short* d_ = lds + (Q) * BUFEL + (OFF) + tid * 8;                             \
    __builtin_amdgcn_global_load_lds(GPTR((G) + (long)(KT) * BK), SPTR(d_), 16, 0, 0);    \
  } while (0)

  // --- fragment read addressing: row-major [256][16]; lane l: row=base+(l&31),
  //     k-chunk = (l>>5)*8. No swizzle (b128 8-lanes/slot spread is intrinsic).
  const int lr = l & 31;
  const int abase = (wm * 128 + lr) * BK + (l >> 5) * 8;  // + mi*512
  const int bbase = (wn * 64 + lr) * BK + (l >> 5) * 8;   // + ni*512

  f32x16 acc[4][2];
#pragma unroll
  for (int i = 0; i < 4; ++i)
#pragma unroll
    for (int j = 0; j < 2; ++j) acc[i][j] = (f32x16)(0.f);

#define MM(MI, NI, AF, BF) \
  acc[MI][NI] = __builtin_amdgcn_mfma_f32_32x32x16_bf16(AF, BF, acc[MI][NI], 0, 0, 0)

#define BAR() __builtin_amdgcn_s_barrier()
#define SBAR() __builtin_amdgcn_sched_barrier(0)
#define WAITLGKM(N) do { asm volatile("s_waitcnt lgkmcnt(" #N ")" ::: "memory"); SBAR(); } while (0)

  // --- prologue: stage tiles 0 and 1 (4 gloads each); wait tile 0 ---
  STG(AH_OFF, gAh, 0, 0); STG(AL_OFF, gAl, 0, 0);
  STG(BH_OFF, gBh, 0, 0); STG(BL_OFF, gBl, 0, 0);
  STG(AH_OFF, gAh, 1, 1); STG(AL_OFF, gAl, 1, 1);
  STG(BH_OFF, gBh, 1, 1); STG(BL_OFF, gBl, 1, 1);
  asm volatile("s_waitcnt vmcnt(4)" ::: "memory");  // tile 0 landed; tile 1 in flight
  BAR();

  s16x8 Ah[4], Al[4], Bh[2], Bl[2];

  int q = 0;  // read buffer
  for (int kt = 0; kt < NKT; ++kt) {
    const unsigned short* p = lds + q * BUFEL;
    const int qn = (q >= 1) ? q - 1 : 2;  // (q+2)%3 — stage target
    const bool st = (kt + 2) < NKT;

    // entry invariant: buf q (tile kt) fully landed for ALL waves (vmcnt+BAR).
    // G1: Ah(4) + Bh(2) -> feeds B1
#pragma unroll
    for (int mi = 0; mi < 4; ++mi) Ah[mi] = *(const s16x8*)(p + AH_OFF + abase + mi * 512);
#pragma unroll
    for (int ni = 0; ni < 2; ++ni) Bh[ni] = *(const s16x8*)(p + BH_OFF + bbase + ni * 512);
    SBAR();
    // G2: Al(4) + Bl(2) -> feeds B2/B3
#pragma unroll
    for (int mi = 0; mi < 4; ++mi) Al[mi] = *(const s16x8*)(p + AL_OFF + abase + mi * 512);
#pragma unroll
    for (int ni = 0; ni < 2; ++ni) Bl[ni] = *(const s16x8*)(p + BL_OFF + bbase + ni * 512);
    SBAR();
    // stage tile kt+2 into buf qn (4 gloads; drained at end of NEXT kt)
    if (st) { STG(AH_OFF, gAh, qn, kt + 2); STG(AL_OFF, gAl, qn, kt + 2);
              STG(BH_OFF, gBh, qn, kt + 2); STG(BL_OFF, gBl, qn, kt + 2); }
    SBAR();
    // outstanding ds_reads: G1(6)+G2(6)=12 (<=15 field limit)
    WAITLGKM(6);  // G1 done
    __builtin_amdgcn_s_setprio(1);
#pragma unroll
    for (int mi = 0; mi < 4; ++mi)
#pragma unroll
      for (int ni = 0; ni < 2; ++ni) MM(mi, ni, Ah[mi], Bh[ni]);  // B1: hihi (8)
    WAITLGKM(0);  // G2 done (returned under B1)
#pragma unroll
    for (int mi = 0; mi < 4; ++mi)
#pragma unroll
      for (int ni = 0; ni < 2; ++ni) MM(mi, ni, Ah[mi], Bl[ni]);  // B2: hilo (8)
#pragma unroll
    for (int mi = 0; mi < 4; ++mi)
#pragma unroll
      for (int ni = 0; ni < 2; ++ni) MM(mi, ni, Al[mi], Bh[ni]);  // B3: lohi (8)
    __builtin_amdgcn_s_setprio(0);
    // vmcnt ledger: steady outstanding = kt+1(4 oldest) + kt+2(4) -> wait kt+1
    if (st) asm volatile("s_waitcnt vmcnt(4)" ::: "memory");
    else    asm volatile("s_waitcnt vmcnt(0)" ::: "memory");  // tail: drain all
    BAR();  // cross-wave: next tile's buffer landed for ALL waves
    q = (q == 2) ? 0 : q + 1;
  }

  // ---- LIF scan: 4 rounds x 64 timesteps; [col][ST=68] layout ----
  __syncthreads();
  float* scanbuf = reinterpret_cast<float*>(lds);  // [256 cols][68]
  float memv = 0.f;
  int fired = 0;
  const float b1v = (tid < 256) ? b1[hb + tid] : 0.f;

  for (int rnd = 0; rnd < 4; ++rnd) {
    if (wm == (rnd >> 1)) {
      // round covers t in [64*rnd, 64*rnd+64); this wave's mi = mi0, mi0+1
      const int mi0 = (rnd & 1) * 2;
#pragma unroll
      for (int dm = 0; dm < 2; ++dm) {
        const int mi = mi0 + dm;
#pragma unroll
        for (int ni = 0; ni < 2; ++ni) {
          const int col = wn * 64 + ni * 32 + lr;
          // C/D 32x32: t-local = dm*32 + (r&3) + 8*(r>>2) + 4*(l>>5)
          float* dst = scanbuf + col * ST + dm * 32 + 4 * (l >> 5);
#pragma unroll
          for (int rq = 0; rq < 4; ++rq) {
            float4 v;
            v.x = acc[mi][ni][rq * 4 + 0];
            v.y = acc[mi][ni][rq * 4 + 1];
            v.z = acc[mi][ni][rq * 4 + 2];
            v.w = acc[mi][ni][rq * 4 + 3];
            *reinterpret_cast<float4*>(dst + 8 * rq) = v;
          }
        }
      }
    }
    __syncthreads();
    if (tid < 256) {
      const float* src = scanbuf + tid * ST;
      float4 cur = *reinterpret_cast<const float4*>(src);
      for (int t0 = 0; t0 < 64; t0 += 4) {
        const int tn = (t0 + 4 < 64) ? t0 + 4 : t0;
        const float4 nxt = *reinterpret_cast<const float4*>(src + tn);
        float c;
        c = cur.x + b1v; memv = memv * 0.9f + c * 0.1f; fired = memv > 1.0f; if (fired) memv = 0.f;
        c = cur.y + b1v; memv = memv * 0.9f + c * 0.1f; fired = memv > 1.0f; if (fired) memv = 0.f;
        c = cur.z + b1v; memv = memv * 0.9f + c * 0.1f; fired = memv > 1.0f; if (fired) memv = 0.f;
        c = cur.w + b1v; memv = memv * 0.9f + c * 0.1f; fired = memv > 1.0f; if (fired) memv = 0.f;
        cur = nxt;
      }
    }
    __syncthreads();
  }
  if (tid < 256) spk[(long)b * Hsz + hb + tid] = fired ? 1.0f : 0.0f;
}

// ------- kernel 4: out = spk @ W2 + b2, exploiting spike sparsity -------
__global__ void gemm2_kernel(const float* __restrict__ spk, const float* __restrict__ W2,
                             const float* __restrict__ b2, float* __restrict__ out) {
  __shared__ int s_cnt[256];
  __shared__ int s_off[257];
  __shared__ int s_list[Hsz];
  const int b = blockIdx.x;
  const int tid = threadIdx.x;
  int hs[8];
  int c = 0;
#pragma unroll
  for (int e = 0; e < 8; ++e) {
    const int h = tid * 8 + e;
    if (spk[(long)b * Hsz + h] > 0.5f) hs[c++] = h;
  }
  s_cnt[tid] = c;
  __syncthreads();
  if (tid == 0) {
    int s = 0;
    for (int i = 0; i < 256; ++i) { s_off[i] = s; s += s_cnt[i]; }
    s_off[256] = s;
  }
  __syncthreads();
  {
    const int base = s_off[tid];
    for (int i = 0; i < c; ++i) s_list[base + i] = hs[i];
  }
  __syncthreads();
  const int total = s_off[256];
#pragma unroll
  for (int q = 0; q < 4; ++q) {
    const int o = q * 256 + tid;
    float v = b2[o];
    for (int i = 0; i < total; ++i) v += W2[(long)s_list[i] * Osz + o];
    out[(long)b * Osz + o] = v;
  }
}

extern "C" void kernel_launch(void* const* d_in, const int* in_sizes, int n_in,
                              void* d_out, int out_size, void* d_ws, size_t ws_size,
                              hipStream_t stream) {
  const float* x = (const float*)d_in[0];
  const float* W1 = (const float*)d_in[1];
  const float* b1 = (const float*)d_in[2];
  const float* W2 = (const float*)d_in[3];
  const float* b2 = (const float*)d_in[4];
  float* out = (float*)d_out;

  unsigned short* xh = (unsigned short*)d_ws;           // [16384][1024] bf16
  unsigned short* xl = xh + (long)Bsz * Tsz * Isz;
  unsigned short* wh = xl + (long)Bsz * Tsz * Isz;      // [2048][1024] (W1^T)
  unsigned short* wl = wh + (long)Hsz * Isz;
  float* spk = (float*)(wl + (long)Hsz * Isz);          // [64][2048]

  split_x_kernel<<<(Bsz * Tsz * Isz) / (256 * 4), 256, 0, stream>>>(x, xh, xl);
  w1_transpose_split_kernel<<<dim3(Hsz / 32, Isz / 32), 256, 0, stream>>>(W1, wh, wl);
  gemm1_scan_kernel<<<dim3(8, 64), 512, 0, stream>>>(xh, xl, wh, wl, b1, spk);
  gemm2_kernel<<<Bsz, 256, 0, stream>>>(spk, W2, b2, out);
}